// Round 5
// baseline (128.055 us; speedup 1.0000x reference)
//
#include <hip/hip_runtime.h>
#include <hip/hip_fp16.h>
#include <stdint.h>

// Problem constants: Xp(16384,3) X(8192,3) W(64,8192) eps scalar -> out(16384,64)
#define M_ROWS 16384
#define N_PTS  8192
#define K_OUT  64
#define NSPLIT 16
#define SLICE  (N_PTS / NSPLIT)   // 512 points per block

typedef _Float16 h2    __attribute__((ext_vector_type(2)));
typedef _Float16 f16x8 __attribute__((ext_vector_type(8)));
typedef float    f32x4 __attribute__((ext_vector_type(4)));

union AF { f16x8 v; uint4 q; uint32_t u[4]; h2 h[4]; };

__device__ __forceinline__ h2 pkrtz2(float a, float b) {
    return __builtin_bit_cast(h2, __builtin_amdgcn_cvt_pkrtz(a, b));
}
__device__ __forceinline__ uint32_t pkrtz(float a, float b) {
    return __builtin_bit_cast(uint32_t, __builtin_amdgcn_cvt_pkrtz(a, b));
}

// packed fast sqrt(t) for t in [~1, ~512]: f16 rsqrt bit-seed (0x59BA) + 1 Newton,
// phi = t * r1. t >= 1 guarantees (t_bits>>1) < 0x59BA in both halves -> the u32
// subtract never borrows across the half boundary. Rel err <= ~3e-3.
__device__ __forceinline__ h2 pk_sqrt_fast(h2 t) {
    const h2 c15 = {(_Float16)1.5f, (_Float16)1.5f};
    const h2 mhf = {(_Float16)-0.5f, (_Float16)-0.5f};
    uint32_t u = __builtin_bit_cast(uint32_t, t);
    uint32_t r0u = 0x59BA59BAu - ((u >> 1) & 0x7FFF7FFFu);
    h2 r0 = __builtin_bit_cast(h2, r0u);
    h2 hh = t * mhf;                                   // -t/2
    h2 r2 = r0 * r0;
    h2 k  = __builtin_elementwise_fma(hh, r2, c15);    // 1.5 - (t/2) r0^2
    return t * (r0 * k);
}

// ---------------- prep ----------------
// blocks [0,256):   W -> fragment-linear f16 Wt (B-frag order for 16x16x32):
//                   Wt uint4 idx (b*4+kt)*64+lane = W[kt*16+(lane&15)][b*32+(lane>>4)*8+j]
// blocks [256,512): zero d_out
// blocks [512,528): coord streams as packed-f16 pairs (4096 dwords each):
//                   Cx = -2*eps*x, Cy, Cz, Cc = |eps*x|^2 + 1
__global__ __launch_bounds__(256) void rbf_prep(
    const float* __restrict__ Wf, const float* __restrict__ X,
    const float* __restrict__ epsp, float* __restrict__ out,
    uint4* __restrict__ Wt, uint32_t* __restrict__ Cx,
    uint32_t* __restrict__ Cy, uint32_t* __restrict__ Cz,
    uint32_t* __restrict__ Cc)
{
    const int bid = blockIdx.x, tid = threadIdx.x;
    if (bid < 256) {
        const int kt = tid >> 6, lane = tid & 63;
        const int l15 = lane & 15, g = lane >> 4;
        const int row = kt * 16 + l15;
        const int col = bid * 32 + g * 8;
        const float4* src = (const float4*)(Wf + row * N_PTS + col);
        const float4 w0 = src[0], w1 = src[1];
        uint4 p;
        p.x = pkrtz(w0.x, w0.y);
        p.y = pkrtz(w0.z, w0.w);
        p.z = pkrtz(w1.x, w1.y);
        p.w = pkrtz(w1.z, w1.w);
        Wt[(bid * 4 + kt) * 64 + lane] = p;
    } else if (bid < 512) {
        const int i = ((bid - 256) * 256 + tid) * 4;
        const float4 z = make_float4(0.f, 0.f, 0.f, 0.f);
        float4* o = (float4*)out + i;
        o[0] = z; o[1] = z; o[2] = z; o[3] = z;
    } else {
        const int n = (bid - 512) * 256 + tid;       // pair index [0, 4096)
        const float e = *epsp;
        const float2 A = *(const float2*)(X + 6 * n);      // x0 y0
        const float2 B = *(const float2*)(X + 6 * n + 2);  // z0 x1
        const float2 C = *(const float2*)(X + 6 * n + 4);  // y1 z1
        const float x0 = A.x * e, y0 = A.y * e, z0 = B.x * e;
        const float x1 = B.y * e, y1 = C.x * e, z1 = C.y * e;
        Cx[n] = pkrtz(-2.0f * x0, -2.0f * x1);
        Cy[n] = pkrtz(-2.0f * y0, -2.0f * y1);
        Cz[n] = pkrtz(-2.0f * z0, -2.0f * z1);
        Cc[n] = pkrtz(fmaf(x0, x0, fmaf(y0, y0, fmaf(z0, z0, 1.0f))),
                      fmaf(x1, x1, fmaf(y1, y1, fmaf(z1, z1, 1.0f))));
    }
}

// ---------------- main: packed-f16 phi + f16 MFMA ----------------
// 1024 blocks = 64 row-groups x 16 n-slices. Block: 4 waves x 4 row-tiles x 16 rows
// = 256 rows, slice 512 pts. d^2+1 = (cc + a) + px*cx + py*cy + pz*cz in pk_fma,
// phi via pk_sqrt_fast; phi pairs ARE the A-frag dwords (no pack step).
__global__ __launch_bounds__(256, 3) void rbf_main(
    const float* __restrict__ Xp, const uint4* __restrict__ Wt,
    const uint32_t* __restrict__ Cx, const uint32_t* __restrict__ Cy,
    const uint32_t* __restrict__ Cz, const uint32_t* __restrict__ Cc,
    const float* __restrict__ epsp, float* __restrict__ out)
{
    __shared__ __align__(16) uint32_t sC[4 * 256];   // 4 streams x 256 half2 = 4 KB

    const int tid  = threadIdx.x;
    const int lane = tid & 63;
    const int wv   = tid >> 6;
    const int m    = lane & 15;
    const int g    = lane >> 4;

    const int bid = blockIdx.x;
    const int ns  = bid & (NSPLIT - 1);
    const int rg  = bid >> 4;
    const int rowbase = rg * 256 + wv * 16;

    // stage this slice's coord streams into LDS (wave wv handles stream wv)
    {
        const int i = tid & 63;
        const uint32_t* src = (wv == 0) ? Cx : (wv == 1) ? Cy : (wv == 2) ? Cz : Cc;
        *(uint4*)(sC + wv * 256 + i * 4) = *(const uint4*)(src + ns * 256 + i * 4);
    }

    // per-lane row geometry for 4 tiles (rows rowbase + t*64 + m), f16 splat pairs
    const float e = *epsp;
    h2 pxk[4], pyk[4], pzk[4], aak[4];
    #pragma unroll
    for (int t = 0; t < 4; ++t) {
        const int r = rowbase + t * 64 + m;
        const float px = Xp[3 * r + 0] * e;
        const float py = Xp[3 * r + 1] * e;
        const float pz = Xp[3 * r + 2] * e;
        const float a  = fmaf(px, px, fmaf(py, py, pz * pz));
        pxk[t] = pkrtz2(px, px);
        pyk[t] = pkrtz2(py, py);
        pzk[t] = pkrtz2(pz, pz);
        aak[t] = pkrtz2(a, a);
    }

    __syncthreads();

    f32x4 acc[4][4];
    #pragma unroll
    for (int t = 0; t < 4; ++t)
        #pragma unroll
        for (int kt = 0; kt < 4; ++kt)
            acc[t][kt] = (f32x4){0.f, 0.f, 0.f, 0.f};

    // fragment-linear W: uint4 idx ((ns*16+s)*4 + kt)*64 + lane
    const uint4* wb = Wt + ns * (SLICE / 32) * 256 + lane;
    const uint32_t* cbase = sC + g * 4;   // lane's 8 pts = dwords s*16 + g*4 + {0..3}

    #pragma unroll 2
    for (int s = 0; s < SLICE / 32; ++s) {
        const uint4 vx = *(const uint4*)(cbase + s * 16);
        const uint4 vy = *(const uint4*)(cbase + s * 16 + 256);
        const uint4 vz = *(const uint4*)(cbase + s * 16 + 512);
        const uint4 vc = *(const uint4*)(cbase + s * 16 + 768);

        const uint4* wp = wb + s * 256;
        AF w0, w1, w2, w3;
        w0.q = wp[0];
        w1.q = wp[64];
        w2.q = wp[128];
        w3.q = wp[192];

        const h2 cx[4] = {__builtin_bit_cast(h2, vx.x), __builtin_bit_cast(h2, vx.y),
                          __builtin_bit_cast(h2, vx.z), __builtin_bit_cast(h2, vx.w)};
        const h2 cy[4] = {__builtin_bit_cast(h2, vy.x), __builtin_bit_cast(h2, vy.y),
                          __builtin_bit_cast(h2, vy.z), __builtin_bit_cast(h2, vy.w)};
        const h2 cz[4] = {__builtin_bit_cast(h2, vz.x), __builtin_bit_cast(h2, vz.y),
                          __builtin_bit_cast(h2, vz.z), __builtin_bit_cast(h2, vz.w)};
        const h2 cc[4] = {__builtin_bit_cast(h2, vc.x), __builtin_bit_cast(h2, vc.y),
                          __builtin_bit_cast(h2, vc.z), __builtin_bit_cast(h2, vc.w)};

        #pragma unroll
        for (int t = 0; t < 4; ++t) {
            AF af;
            #pragma unroll
            for (int j = 0; j < 4; ++j) {
                h2 d = cc[j] + aak[t];
                d = __builtin_elementwise_fma(pxk[t], cx[j], d);
                d = __builtin_elementwise_fma(pyk[t], cy[j], d);
                d = __builtin_elementwise_fma(pzk[t], cz[j], d);
                af.h[j] = pk_sqrt_fast(d);
            }
            acc[t][0] = __builtin_amdgcn_mfma_f32_16x16x32_f16(af.v, w0.v, acc[t][0], 0, 0, 0);
            acc[t][1] = __builtin_amdgcn_mfma_f32_16x16x32_f16(af.v, w1.v, acc[t][1], 0, 0, 0);
            acc[t][2] = __builtin_amdgcn_mfma_f32_16x16x32_f16(af.v, w2.v, acc[t][2], 0, 0, 0);
            acc[t][3] = __builtin_amdgcn_mfma_f32_16x16x32_f16(af.v, w3.v, acc[t][3], 0, 0, 0);
        }
    }

    // C/D: col = kt*16 + m, row = rowbase + t*64 + g*4 + reg. 16 partials -> atomicAdd.
    #pragma unroll
    for (int t = 0; t < 4; ++t) {
        float* o = out + (rowbase + t * 64 + g * 4) * K_OUT + m;
        #pragma unroll
        for (int reg = 0; reg < 4; ++reg) {
            atomicAdd(o + reg * K_OUT +  0, acc[t][0][reg]);
            atomicAdd(o + reg * K_OUT + 16, acc[t][1][reg]);
            atomicAdd(o + reg * K_OUT + 32, acc[t][2][reg]);
            atomicAdd(o + reg * K_OUT + 48, acc[t][3][reg]);
        }
    }
}

extern "C" void kernel_launch(void* const* d_in, const int* in_sizes, int n_in,
                              void* d_out, int out_size, void* d_ws, size_t ws_size,
                              hipStream_t stream) {
    (void)in_sizes; (void)n_in; (void)out_size; (void)ws_size;
    const float* Xp  = (const float*)d_in[0];   // (16384,3)
    const float* X   = (const float*)d_in[1];   // (8192,3)
    const float* Wf  = (const float*)d_in[2];   // (64,8192)
    const float* eps = (const float*)d_in[3];   // scalar
    float* out = (float*)d_out;                 // (16384,64)

    // ws: Wt (fragment-linear f16 W) 1 MiB | Cx,Cy,Cz,Cc 16 KiB each
    uint4*    Wt = (uint4*)d_ws;
    uint32_t* Cx = (uint32_t*)((char*)d_ws + (1u << 20));
    uint32_t* Cy = Cx + 4096;
    uint32_t* Cz = Cy + 4096;
    uint32_t* Cc = Cz + 4096;

    rbf_prep<<<dim3(528), dim3(256), 0, stream>>>(Wf, X, eps, out, Wt, Cx, Cy, Cz, Cc);
    rbf_main<<<dim3((M_ROWS / 256) * NSPLIT), dim3(256), 0, stream>>>(
        Xp, Wt, Cx, Cy, Cz, Cc, eps, out);
}

// Round 6
// 99.229 us; speedup vs baseline: 1.2905x; 1.2905x over previous
//
#include <hip/hip_runtime.h>
#include <hip/hip_fp16.h>
#include <stdint.h>

// Problem constants: Xp(16384,3) X(8192,3) W(64,8192) eps scalar -> out(16384,64)
#define M_ROWS 16384
#define N_PTS  8192
#define K_OUT  64

typedef _Float16 h2    __attribute__((ext_vector_type(2)));
typedef _Float16 f16x8 __attribute__((ext_vector_type(8)));
typedef float    f32x4 __attribute__((ext_vector_type(4)));

union AF { f16x8 v; uint4 q; uint32_t u[4]; h2 h[4]; };

__device__ __forceinline__ h2 pkrtz2(float a, float b) {
    return __builtin_bit_cast(h2, __builtin_amdgcn_cvt_pkrtz(a, b));
}
__device__ __forceinline__ uint32_t pkrtz(float a, float b) {
    return __builtin_bit_cast(uint32_t, __builtin_amdgcn_cvt_pkrtz(a, b));
}

// packed fast sqrt(t) for t in [1, ~512]: f16 rsqrt bit-seed (0x59BA) + 1 Newton,
// phi = t * r1. t >= 1 -> (t_bits>>1) < 0x59BA in both halves, so the u32 subtract
// never borrows across the half boundary. Rel err <= ~3e-3. (validated r5, absmax 8)
__device__ __forceinline__ h2 pk_sqrt_fast(h2 t) {
    const h2 c15 = {(_Float16)1.5f, (_Float16)1.5f};
    const h2 mhf = {(_Float16)-0.5f, (_Float16)-0.5f};
    uint32_t u = __builtin_bit_cast(uint32_t, t);
    uint32_t r0u = 0x59BA59BAu - ((u >> 1) & 0x7FFF7FFFu);
    h2 r0 = __builtin_bit_cast(h2, r0u);
    h2 hh = t * mhf;
    h2 r2 = r0 * r0;
    h2 k  = __builtin_elementwise_fma(hh, r2, c15);    // 1.5 - (t/2) r0^2
    return t * (r0 * k);
}

// ---------------- prep ----------------
// blocks [0,256):   W -> fragment-linear f16 Wt (B-frag order for 16x16x32):
//                   Wt uint4 idx (b*4+kt)*64+lane = W[kt*16+(lane&15)][b*32+(lane>>4)*8+j]
// blocks [256,272): coord streams as packed-f16 pairs (4096 dwords each):
//                   Cx = -2*eps*x, Cy, Cz, Cc = |eps*x|^2 + 1
// (no out zeroing needed: main writes every output exactly once)
__global__ __launch_bounds__(256) void rbf_prep(
    const float* __restrict__ Wf, const float* __restrict__ X,
    const float* __restrict__ epsp,
    uint4* __restrict__ Wt, uint32_t* __restrict__ Cx,
    uint32_t* __restrict__ Cy, uint32_t* __restrict__ Cz,
    uint32_t* __restrict__ Cc)
{
    const int bid = blockIdx.x, tid = threadIdx.x;
    if (bid < 256) {
        const int kt = tid >> 6, lane = tid & 63;
        const int l15 = lane & 15, g = lane >> 4;
        const int row = kt * 16 + l15;
        const int col = bid * 32 + g * 8;
        const float4* src = (const float4*)(Wf + row * N_PTS + col);
        const float4 w0 = src[0], w1 = src[1];
        uint4 p;
        p.x = pkrtz(w0.x, w0.y);
        p.y = pkrtz(w0.z, w0.w);
        p.z = pkrtz(w1.x, w1.y);
        p.w = pkrtz(w1.z, w1.w);
        Wt[(bid * 4 + kt) * 64 + lane] = p;
    } else {
        const int n = (bid - 256) * 256 + tid;       // pair index [0, 4096)
        const float e = *epsp;
        const float2 A = *(const float2*)(X + 6 * n);      // x0 y0
        const float2 B = *(const float2*)(X + 6 * n + 2);  // z0 x1
        const float2 C = *(const float2*)(X + 6 * n + 4);  // y1 z1
        const float x0 = A.x * e, y0 = A.y * e, z0 = B.x * e;
        const float x1 = B.y * e, y1 = C.x * e, z1 = C.y * e;
        Cx[n] = pkrtz(-2.0f * x0, -2.0f * x1);
        Cy[n] = pkrtz(-2.0f * y0, -2.0f * y1);
        Cz[n] = pkrtz(-2.0f * z0, -2.0f * z1);
        Cc[n] = pkrtz(fmaf(x0, x0, fmaf(y0, y0, fmaf(z0, z0, 1.0f))),
                      fmaf(x1, x1, fmaf(y1, y1, fmaf(z1, z1, 1.0f))));
    }
}

// ---------------- main: split-N in-block, LDS cross-wave reduce, NO atomics ----------
// 512 blocks x 512 threads. Block owns rows [bid*32, bid*32+32) (2 row-tiles/wave).
// Wave wv covers points [wv*1024, (wv+1)*1024): 32 iters of 32 pts, 8 MFMA each.
// Epilogue: 8 waves' partials summed through 64 KB LDS, plain coalesced stores.
__global__ __launch_bounds__(512, 4) void rbf_main(
    const float* __restrict__ Xp, const uint4* __restrict__ Wt,
    const uint32_t* __restrict__ Cx, const uint32_t* __restrict__ Cy,
    const uint32_t* __restrict__ Cz, const uint32_t* __restrict__ Cc,
    const float* __restrict__ epsp, float* __restrict__ out)
{
    __shared__ __align__(16) float sR[8 * 32 * 64];   // 64 KB: [wave][row(32)][col(64)]

    const int tid  = threadIdx.x;
    const int lane = tid & 63;
    const int wv   = tid >> 6;        // 0..7 = n-chunk
    const int m    = lane & 15;
    const int g    = lane >> 4;

    const int rowbase = blockIdx.x * 32;

    // per-lane row geometry for 2 tiles (rows rowbase + t*16 + m), f16 splat pairs
    const float e = *epsp;
    h2 pxk[2], pyk[2], pzk[2], aak[2];
    #pragma unroll
    for (int t = 0; t < 2; ++t) {
        const int r = rowbase + t * 16 + m;
        const float px = Xp[3 * r + 0] * e;
        const float py = Xp[3 * r + 1] * e;
        const float pz = Xp[3 * r + 2] * e;
        const float a  = fmaf(px, px, fmaf(py, py, pz * pz));
        pxk[t] = pkrtz2(px, px);
        pyk[t] = pkrtz2(py, py);
        pzk[t] = pkrtz2(pz, pz);
        aak[t] = pkrtz2(a, a);
    }

    f32x4 acc[2][4];
    #pragma unroll
    for (int t = 0; t < 2; ++t)
        #pragma unroll
        for (int kt = 0; kt < 4; ++kt)
            acc[t][kt] = (f32x4){0.f, 0.f, 0.f, 0.f};

    // coord streams: dword base for this wave/lane (1024 pts = 512 dwords per wave)
    const uint32_t* cxp = Cx + wv * 512 + g * 4;
    const uint32_t* cyp = Cy + wv * 512 + g * 4;
    const uint32_t* czp = Cz + wv * 512 + g * 4;
    const uint32_t* ccp = Cc + wv * 512 + g * 4;
    // fragment-linear W: uint4 idx = ((wv*32 + s)*4 + kt)*64 + lane
    const uint4* wb = Wt + wv * 32 * 256 + lane;

    // prologue: load s=0
    uint4 vx = *(const uint4*)cxp;
    uint4 vy = *(const uint4*)cyp;
    uint4 vz = *(const uint4*)czp;
    uint4 vc = *(const uint4*)ccp;
    uint4 w0 = wb[0], w1 = wb[64], w2 = wb[128], w3 = wb[192];

    for (int s = 0; s < 32; ++s) {
        // prefetch s+1 (wraps on last iter — harmless redundant load)
        const int sn = (s + 1) & 31;
        const uint4 nvx = *(const uint4*)(cxp + sn * 16);
        const uint4 nvy = *(const uint4*)(cyp + sn * 16);
        const uint4 nvz = *(const uint4*)(czp + sn * 16);
        const uint4 nvc = *(const uint4*)(ccp + sn * 16);
        const uint4* nwp = wb + sn * 256;
        const uint4 nw0 = nwp[0], nw1 = nwp[64], nw2 = nwp[128], nw3 = nwp[192];

        const h2 cx[4] = {__builtin_bit_cast(h2, vx.x), __builtin_bit_cast(h2, vx.y),
                          __builtin_bit_cast(h2, vx.z), __builtin_bit_cast(h2, vx.w)};
        const h2 cy[4] = {__builtin_bit_cast(h2, vy.x), __builtin_bit_cast(h2, vy.y),
                          __builtin_bit_cast(h2, vy.z), __builtin_bit_cast(h2, vy.w)};
        const h2 cz[4] = {__builtin_bit_cast(h2, vz.x), __builtin_bit_cast(h2, vz.y),
                          __builtin_bit_cast(h2, vz.z), __builtin_bit_cast(h2, vz.w)};
        const h2 cc[4] = {__builtin_bit_cast(h2, vc.x), __builtin_bit_cast(h2, vc.y),
                          __builtin_bit_cast(h2, vc.z), __builtin_bit_cast(h2, vc.w)};

        AF wf0, wf1, wf2, wf3;
        wf0.q = w0; wf1.q = w1; wf2.q = w2; wf3.q = w3;

        #pragma unroll
        for (int t = 0; t < 2; ++t) {
            AF af;
            #pragma unroll
            for (int j = 0; j < 4; ++j) {
                h2 d = cc[j] + aak[t];
                d = __builtin_elementwise_fma(pxk[t], cx[j], d);
                d = __builtin_elementwise_fma(pyk[t], cy[j], d);
                d = __builtin_elementwise_fma(pzk[t], cz[j], d);
                af.h[j] = pk_sqrt_fast(d);
            }
            acc[t][0] = __builtin_amdgcn_mfma_f32_16x16x32_f16(af.v, wf0.v, acc[t][0], 0, 0, 0);
            acc[t][1] = __builtin_amdgcn_mfma_f32_16x16x32_f16(af.v, wf1.v, acc[t][1], 0, 0, 0);
            acc[t][2] = __builtin_amdgcn_mfma_f32_16x16x32_f16(af.v, wf2.v, acc[t][2], 0, 0, 0);
            acc[t][3] = __builtin_amdgcn_mfma_f32_16x16x32_f16(af.v, wf3.v, acc[t][3], 0, 0, 0);
        }

        vx = nvx; vy = nvy; vz = nvz; vc = nvc;
        w0 = nw0; w1 = nw1; w2 = nw2; w3 = nw3;
    }

    // ---- cross-wave reduction through LDS ----
    // D layout: value acc[t][kt][reg] = partial out[rowbase + t*16 + g*4 + reg][kt*16 + m]
    {
        float* base = sR + wv * 2048;
        #pragma unroll
        for (int t = 0; t < 2; ++t)
            #pragma unroll
            for (int kt = 0; kt < 4; ++kt)
                #pragma unroll
                for (int reg = 0; reg < 4; ++reg)
                    base[(t * 16 + g * 4 + reg) * 64 + kt * 16 + m] = acc[t][kt][reg];
    }
    __syncthreads();

    // 512 threads: thread -> (row = tid>>4 in [0,32), kq = tid&15), sum 8 waves, store
    {
        const int row = tid >> 4;
        const int kq  = tid & 15;
        const float* p = sR + row * 64 + kq * 4;
        float4 s0 = *(const float4*)(p);
        #pragma unroll
        for (int w = 1; w < 8; ++w) {
            const float4 sw = *(const float4*)(p + w * 2048);
            s0.x += sw.x; s0.y += sw.y; s0.z += sw.z; s0.w += sw.w;
        }
        *(float4*)(out + (rowbase + row) * K_OUT + kq * 4) = s0;
    }
}

extern "C" void kernel_launch(void* const* d_in, const int* in_sizes, int n_in,
                              void* d_out, int out_size, void* d_ws, size_t ws_size,
                              hipStream_t stream) {
    (void)in_sizes; (void)n_in; (void)out_size; (void)ws_size;
    const float* Xp  = (const float*)d_in[0];   // (16384,3)
    const float* X   = (const float*)d_in[1];   // (8192,3)
    const float* Wf  = (const float*)d_in[2];   // (64,8192)
    const float* eps = (const float*)d_in[3];   // scalar
    float* out = (float*)d_out;                 // (16384,64)

    // ws: Wt (fragment-linear f16 W) 1 MiB | Cx,Cy,Cz,Cc 16 KiB each
    uint4*    Wt = (uint4*)d_ws;
    uint32_t* Cx = (uint32_t*)((char*)d_ws + (1u << 20));
    uint32_t* Cy = Cx + 4096;
    uint32_t* Cz = Cy + 4096;
    uint32_t* Cc = Cz + 4096;

    rbf_prep<<<dim3(272), dim3(256), 0, stream>>>(Wf, X, eps, Wt, Cx, Cy, Cz, Cc);
    rbf_main<<<dim3(M_ROWS / 32), dim3(512), 0, stream>>>(
        Xp, Wt, Cx, Cy, Cz, Cc, eps, out);
}

// Round 7
// 96.716 us; speedup vs baseline: 1.3240x; 1.0260x over previous
//
#include <hip/hip_runtime.h>
#include <hip/hip_fp16.h>
#include <stdint.h>

// Problem constants: Xp(16384,3) X(8192,3) W(64,8192) eps scalar -> out(16384,64)
#define M_ROWS 16384
#define N_PTS  8192
#define K_OUT  64

typedef _Float16       h2    __attribute__((ext_vector_type(2)));
typedef unsigned short u16x2 __attribute__((ext_vector_type(2)));
typedef _Float16       f16x8 __attribute__((ext_vector_type(8)));
typedef float          f32x4 __attribute__((ext_vector_type(4)));

union AF { f16x8 v; uint4 q; uint32_t u[4]; h2 h[4]; };

__device__ __forceinline__ h2 pkrtz2(float a, float b) {
    return __builtin_bit_cast(h2, __builtin_amdgcn_cvt_pkrtz(a, b));
}
__device__ __forceinline__ uint32_t pkrtz(float a, float b) {
    return __builtin_bit_cast(uint32_t, __builtin_amdgcn_cvt_pkrtz(a, b));
}

// packed fast sqrt(t), t in [1, ~512]: per-half rsqrt bit-seed (0x59BA - (u>>1),
// packed 16-bit ops so no cross-half contamination) + 1 reassociated Newton:
// y = t*r0; p = y*r0; k = 1.5 - 0.5*p; phi = y*k.  6 packed VALU ops / 2 phis.
// Rel err <= ~3e-3 (r5/r6 validated the same math, absmax 8 vs threshold 21.28).
__device__ __forceinline__ h2 pk_sqrt_fast(h2 t, h2 mhf, h2 c15) {
    u16x2 u = __builtin_bit_cast(u16x2, t);
    u16x2 r0u = (u16x2){0x59BA, 0x59BA} - (u >> 1);
    h2 r0 = __builtin_bit_cast(h2, r0u);
    h2 y = t * r0;
    h2 p = y * r0;
    h2 k = __builtin_elementwise_fma(p, mhf, c15);
    return y * k;
}

// ---------------- prep ----------------
// blocks [0,256):   W -> fragment-linear f16 Wt (B-frag order for 16x16x32):
//                   Wt uint4 idx (b*4+kt)*64+lane = W[kt*16+(lane&15)][b*32+(lane>>4)*8+j]
// blocks [256,272): coord streams as packed-f16 pairs (4096 dwords each):
//                   Cx = -2*eps*x, Cy, Cz, Cc = |eps*x|^2 + 1
__global__ __launch_bounds__(256) void rbf_prep(
    const float* __restrict__ Wf, const float* __restrict__ X,
    const float* __restrict__ epsp,
    uint4* __restrict__ Wt, uint32_t* __restrict__ Cx,
    uint32_t* __restrict__ Cy, uint32_t* __restrict__ Cz,
    uint32_t* __restrict__ Cc)
{
    const int bid = blockIdx.x, tid = threadIdx.x;
    if (bid < 256) {
        const int kt = tid >> 6, lane = tid & 63;
        const int l15 = lane & 15, g = lane >> 4;
        const int row = kt * 16 + l15;
        const int col = bid * 32 + g * 8;
        const float4* src = (const float4*)(Wf + row * N_PTS + col);
        const float4 w0 = src[0], w1 = src[1];
        uint4 p;
        p.x = pkrtz(w0.x, w0.y);
        p.y = pkrtz(w0.z, w0.w);
        p.z = pkrtz(w1.x, w1.y);
        p.w = pkrtz(w1.z, w1.w);
        Wt[(bid * 4 + kt) * 64 + lane] = p;
    } else {
        const int n = (bid - 256) * 256 + tid;       // pair index [0, 4096)
        const float e = *epsp;
        const float2 A = *(const float2*)(X + 6 * n);      // x0 y0
        const float2 B = *(const float2*)(X + 6 * n + 2);  // z0 x1
        const float2 C = *(const float2*)(X + 6 * n + 4);  // y1 z1
        const float x0 = A.x * e, y0 = A.y * e, z0 = B.x * e;
        const float x1 = B.y * e, y1 = C.x * e, z1 = C.y * e;
        Cx[n] = pkrtz(-2.0f * x0, -2.0f * x1);
        Cy[n] = pkrtz(-2.0f * y0, -2.0f * y1);
        Cz[n] = pkrtz(-2.0f * z0, -2.0f * z1);
        Cc[n] = pkrtz(fmaf(x0, x0, fmaf(y0, y0, fmaf(z0, z0, 1.0f))),
                      fmaf(x1, x1, fmaf(y1, y1, fmaf(z1, z1, 1.0f))));
    }
}

// ---------------- main: split-N in-block, LDS cross-wave reduce, no atomics --------
// 512 blocks x 512 threads (2 blocks/CU, LDS-limited). Block owns rows
// [bid*32, bid*32+32) as 2 row-tiles/wave; wave wv covers points [wv*1024,...).
// Addressing: uniform SGPR bases + fixed lane voffsets + immediate offsets —
// near-zero per-iter VALU address cost. No manual prefetch/rotation (that cost
// ~130 VALU/iter in r6); unroll 8 lets the compiler hoist loads.
__global__ __launch_bounds__(512, 4) void rbf_main(
    const float* __restrict__ Xp, const uint4* __restrict__ Wt,
    const uint32_t* __restrict__ Cx, const uint32_t* __restrict__ Cy,
    const uint32_t* __restrict__ Cz, const uint32_t* __restrict__ Cc,
    const float* __restrict__ epsp, float* __restrict__ out)
{
    __shared__ __align__(16) float sR[8 * 32 * 64];   // 64 KB: [wave][row(32)][col(64)]

    const int tid  = threadIdx.x;
    const int lane = tid & 63;
    const int wv   = tid >> 6;        // 0..7 = n-chunk
    const int m    = lane & 15;
    const int g    = lane >> 4;

    const int rowbase = blockIdx.x * 32;

    // per-lane row geometry for 2 tiles (rows rowbase + t*16 + m), f16 splat pairs
    const float e = *epsp;
    h2 pxk[2], pyk[2], pzk[2], aak[2];
    #pragma unroll
    for (int t = 0; t < 2; ++t) {
        const int r = rowbase + t * 16 + m;
        const float px = Xp[3 * r + 0] * e;
        const float py = Xp[3 * r + 1] * e;
        const float pz = Xp[3 * r + 2] * e;
        const float a  = fmaf(px, px, fmaf(py, py, pz * pz));
        pxk[t] = pkrtz2(px, px);
        pyk[t] = pkrtz2(py, py);
        pzk[t] = pkrtz2(pz, pz);
        aak[t] = pkrtz2(a, a);
    }
    const h2 mhf = {(_Float16)-0.5f, (_Float16)-0.5f};
    const h2 c15 = {(_Float16)1.5f, (_Float16)1.5f};

    f32x4 acc[2][4];
    #pragma unroll
    for (int t = 0; t < 2; ++t)
        #pragma unroll
        for (int kt = 0; kt < 4; ++kt)
            acc[t][kt] = (f32x4){0.f, 0.f, 0.f, 0.f};

    // uniform bases (wv, block only) — divergent part is a FIXED lane offset
    const uint32_t* cxp = Cx + wv * 512 + g * 4;   // + s*16 (imm, <= 1984 B)
    const uint32_t* cyp = Cy + wv * 512 + g * 4;
    const uint32_t* czp = Cz + wv * 512 + g * 4;
    const uint32_t* ccp = Cc + wv * 512 + g * 4;
    const uint4*    wp  = Wt + wv * 8192 + lane;   // + s*256 (SGPR) + kt*64 (imm)

    #pragma unroll 8
    for (int s = 0; s < 32; ++s) {
        const uint4 vx = *(const uint4*)(cxp + s * 16);
        const uint4 vy = *(const uint4*)(cyp + s * 16);
        const uint4 vz = *(const uint4*)(czp + s * 16);
        const uint4 vc = *(const uint4*)(ccp + s * 16);

        AF wf0, wf1, wf2, wf3;
        wf0.q = wp[s * 256];
        wf1.q = wp[s * 256 + 64];
        wf2.q = wp[s * 256 + 128];
        wf3.q = wp[s * 256 + 192];

        const h2 cx[4] = {__builtin_bit_cast(h2, vx.x), __builtin_bit_cast(h2, vx.y),
                          __builtin_bit_cast(h2, vx.z), __builtin_bit_cast(h2, vx.w)};
        const h2 cy[4] = {__builtin_bit_cast(h2, vy.x), __builtin_bit_cast(h2, vy.y),
                          __builtin_bit_cast(h2, vy.z), __builtin_bit_cast(h2, vy.w)};
        const h2 cz[4] = {__builtin_bit_cast(h2, vz.x), __builtin_bit_cast(h2, vz.y),
                          __builtin_bit_cast(h2, vz.z), __builtin_bit_cast(h2, vz.w)};
        const h2 cc[4] = {__builtin_bit_cast(h2, vc.x), __builtin_bit_cast(h2, vc.y),
                          __builtin_bit_cast(h2, vc.z), __builtin_bit_cast(h2, vc.w)};

        #pragma unroll
        for (int t = 0; t < 2; ++t) {
            AF af;
            #pragma unroll
            for (int j = 0; j < 4; ++j) {
                h2 d = cc[j] + aak[t];
                d = __builtin_elementwise_fma(pxk[t], cx[j], d);
                d = __builtin_elementwise_fma(pyk[t], cy[j], d);
                d = __builtin_elementwise_fma(pzk[t], cz[j], d);
                af.h[j] = pk_sqrt_fast(d, mhf, c15);
            }
            acc[t][0] = __builtin_amdgcn_mfma_f32_16x16x32_f16(af.v, wf0.v, acc[t][0], 0, 0, 0);
            acc[t][1] = __builtin_amdgcn_mfma_f32_16x16x32_f16(af.v, wf1.v, acc[t][1], 0, 0, 0);
            acc[t][2] = __builtin_amdgcn_mfma_f32_16x16x32_f16(af.v, wf2.v, acc[t][2], 0, 0, 0);
            acc[t][3] = __builtin_amdgcn_mfma_f32_16x16x32_f16(af.v, wf3.v, acc[t][3], 0, 0, 0);
        }
    }

    // ---- cross-wave reduction through LDS ----
    // D layout: acc[t][kt][reg] = partial out[rowbase + t*16 + g*4 + reg][kt*16 + m]
    {
        float* base = sR + wv * 2048;
        #pragma unroll
        for (int t = 0; t < 2; ++t)
            #pragma unroll
            for (int kt = 0; kt < 4; ++kt)
                #pragma unroll
                for (int reg = 0; reg < 4; ++reg)
                    base[(t * 16 + g * 4 + reg) * 64 + kt * 16 + m] = acc[t][kt][reg];
    }
    __syncthreads();

    // 512 threads: thread -> (row = tid>>4, kq = tid&15), sum 8 waves, store
    {
        const int row = tid >> 4;
        const int kq  = tid & 15;
        const float* p = sR + row * 64 + kq * 4;
        float4 s0 = *(const float4*)(p);
        #pragma unroll
        for (int w = 1; w < 8; ++w) {
            const float4 sw = *(const float4*)(p + w * 2048);
            s0.x += sw.x; s0.y += sw.y; s0.z += sw.z; s0.w += sw.w;
        }
        *(float4*)(out + (rowbase + row) * K_OUT + kq * 4) = s0;
    }
}

extern "C" void kernel_launch(void* const* d_in, const int* in_sizes, int n_in,
                              void* d_out, int out_size, void* d_ws, size_t ws_size,
                              hipStream_t stream) {
    (void)in_sizes; (void)n_in; (void)out_size; (void)ws_size;
    const float* Xp  = (const float*)d_in[0];   // (16384,3)
    const float* X   = (const float*)d_in[1];   // (8192,3)
    const float* Wf  = (const float*)d_in[2];   // (64,8192)
    const float* eps = (const float*)d_in[3];   // scalar
    float* out = (float*)d_out;                 // (16384,64)

    // ws: Wt (fragment-linear f16 W) 1 MiB | Cx,Cy,Cz,Cc 16 KiB each
    uint4*    Wt = (uint4*)d_ws;
    uint32_t* Cx = (uint32_t*)((char*)d_ws + (1u << 20));
    uint32_t* Cy = Cx + 4096;
    uint32_t* Cz = Cy + 4096;
    uint32_t* Cc = Cz + 4096;

    rbf_prep<<<dim3(272), dim3(256), 0, stream>>>(Wf, X, eps, Wt, Cx, Cy, Cz, Cc);
    rbf_main<<<dim3(M_ROWS / 32), dim3(512), 0, stream>>>(
        Xp, Wt, Cx, Cy, Cz, Cc, eps, out);
}